// Round 2
// baseline (215.982 us; speedup 1.0000x reference)
//
#include <hip/hip_runtime.h>
#include <math.h>

#define NN 1024
#define CC 256
#define TT 64

// ---------------- kernel 1: fused time-mean + row norm ----------------
// 2048 blocks: block b handles tensor (b>>10), row (b&1023). 256 threads.
// Reads a contiguous 64KB (T=64 x C=256 fp32) per block, fully coalesced,
// 16 independent float4 loads per thread -> deep MLP at 32 waves/CU.
__global__ __launch_bounds__(256) void mean_norm_kernel(
    const float* __restrict__ in0, const float* __restrict__ in1,
    float* __restrict__ x, float* __restrict__ y,
    float* __restrict__ nx, float* __restrict__ ny) {
  int b = blockIdx.x;
  int m = b >> 10;
  int n = b & (NN - 1);
  const float* in = (m ? in1 : in0) + (size_t)n * (TT * CC);
  float* xo = m ? y : x;
  float* no = m ? ny : nx;
  int tid = threadIdx.x;
  int c4 = tid & 63;            // float4 channel index (64 per row)
  int tq = tid >> 6;            // wave id = time-quarter
  const float4* src = (const float4*)in + c4;
  float4 s = make_float4(0.f, 0.f, 0.f, 0.f);
  #pragma unroll
  for (int t = 0; t < 16; ++t) {
    float4 v = src[(tq * 16 + t) * (CC / 4)];
    s.x += v.x; s.y += v.y; s.z += v.z; s.w += v.w;
  }
  __shared__ float4 red[3][64];
  if (tq) red[tq - 1][c4] = s;
  __syncthreads();
  if (tq == 0) {
    #pragma unroll
    for (int w = 0; w < 3; ++w) {
      float4 v = red[w][c4];
      s.x += v.x; s.y += v.y; s.z += v.z; s.w += v.w;
    }
    const float inv = 1.0f / TT;
    s.x *= inv; s.y *= inv; s.z *= inv; s.w *= inv;
    ((float4*)(xo + (size_t)n * CC))[c4] = s;
    float ssq = fmaf(s.x, s.x, fmaf(s.y, s.y, fmaf(s.z, s.z, s.w * s.w)));
    #pragma unroll
    for (int o = 32; o > 0; o >>= 1) ssq += __shfl_down(ssq, o, 64);
    if (tid == 0) no[n] = ssq;
  }
}

// ---------------- kernel 2: fused pairwise-distance + reductions ----------------
// Never materializes D. Block tile: 32 rows x 64 cols, 4 waves, each wave
// 8 rows x 64 cols (lane = column). Both matrices (x,y) in one block so each
// thread has (Dx_ij, Dy_ij) locally for the product sums.
// a-operand (rows): wave-uniform scalar loads (SMEM pipe, free vs LDS).
// b-operand (cols): LDS, pad 65 -> (lane+ch)%32 banks = 2-way = free.
// Outputs: atomic row sums Rx,Ry and per-block partials pab/paa/pbb.
__global__ __launch_bounds__(256) void dist_kernel(
    const float* __restrict__ x, const float* __restrict__ y,
    const float* __restrict__ nx, const float* __restrict__ ny,
    float* __restrict__ Rx, float* __restrict__ Ry,
    float* __restrict__ pab, float* __restrict__ paa, float* __restrict__ pbb) {
  int lane = threadIdx.x & 63;
  int wave = __builtin_amdgcn_readfirstlane(threadIdx.x >> 6);
  int tj = blockIdx.x * 64;                 // column tile
  int ti = blockIdx.y * 32;                 // row tile
  int row0 = ti + wave * 8;

  __shared__ float sbx[64][65];
  __shared__ float sby[64][65];

  float accx[8] = {0.f,0.f,0.f,0.f,0.f,0.f,0.f,0.f};
  float accy[8] = {0.f,0.f,0.f,0.f,0.f,0.f,0.f,0.f};

  const float* xrow = x + (size_t)row0 * CC;
  const float* yrow = y + (size_t)row0 * CC;

  for (int kc = 0; kc < CC; kc += 64) {
    if (kc) __syncthreads();
    #pragma unroll
    for (int s = 0; s < 4; ++s) {
      int f4 = threadIdx.x + s * 256;       // 0..1023
      int j = f4 >> 4;                      // staged column 0..63
      int c4 = f4 & 15;                     // float4 within 64-ch chunk
      float4 vx = *(const float4*)(x + (size_t)(tj + j) * CC + kc + c4 * 4);
      sbx[j][c4 * 4 + 0] = vx.x; sbx[j][c4 * 4 + 1] = vx.y;
      sbx[j][c4 * 4 + 2] = vx.z; sbx[j][c4 * 4 + 3] = vx.w;
      float4 vy = *(const float4*)(y + (size_t)(tj + j) * CC + kc + c4 * 4);
      sby[j][c4 * 4 + 0] = vy.x; sby[j][c4 * 4 + 1] = vy.y;
      sby[j][c4 * 4 + 2] = vy.z; sby[j][c4 * 4 + 3] = vy.w;
    }
    __syncthreads();
    #pragma unroll 8
    for (int ch = 0; ch < 64; ++ch) {
      float bx = sbx[lane][ch];
      float by = sby[lane][ch];
      #pragma unroll
      for (int p = 0; p < 8; ++p) {
        accx[p] = fmaf(xrow[p * CC + kc + ch], bx, accx[p]);
        accy[p] = fmaf(yrow[p * CC + kc + ch], by, accy[p]);
      }
    }
  }

  float njx = nx[tj + lane];
  float njy = ny[tj + lane];
  float ab = 0.f, aa = 0.f, bb = 0.f;
  #pragma unroll
  for (int p = 0; p < 8; ++p) {
    float nix = nx[row0 + p];
    float niy = ny[row0 + p];
    float dxv = sqrtf(fmaxf(nix + njx - 2.f * accx[p], 0.f) + 1e-12f);
    float dyv = sqrtf(fmaxf(niy + njy - 2.f * accy[p], 0.f) + 1e-12f);
    ab = fmaf(dxv, dyv, ab);
    aa = fmaf(dxv, dxv, aa);
    bb = fmaf(dyv, dyv, bb);
    float sx_ = dxv, sy_ = dyv;
    #pragma unroll
    for (int o = 32; o > 0; o >>= 1) {
      sx_ += __shfl_down(sx_, o, 64);
      sy_ += __shfl_down(sy_, o, 64);
    }
    if (lane == 0) {
      atomicAdd(&Rx[row0 + p], sx_);
      atomicAdd(&Ry[row0 + p], sy_);
    }
  }
  #pragma unroll
  for (int o = 32; o > 0; o >>= 1) {
    ab += __shfl_down(ab, o, 64);
    aa += __shfl_down(aa, o, 64);
    bb += __shfl_down(bb, o, 64);
  }
  if (lane == 0) {
    int blk = blockIdx.y * 16 + blockIdx.x;   // 0..511
    atomicAdd(&pab[blk], ab);
    atomicAdd(&paa[blk], aa);
    atomicAdd(&pbb[blk], bb);
  }
}

// ---------------- kernel 3: finalize ----------------
// <A,B> = S(DxDy) - (2/n) S(Rx Ry) + Sx Sy / n^2   (H idempotent, D symmetric)
__global__ __launch_bounds__(256) void finalize_kernel(
    const float* __restrict__ Rx, const float* __restrict__ Ry,
    const float* __restrict__ pab, const float* __restrict__ paa,
    const float* __restrict__ pbb, float* __restrict__ out) {
  int tid = threadIdx.x;
  double sx = 0, sy = 0, srr = 0, sxx = 0, syy = 0;
  for (int i = tid; i < NN; i += 256) {
    double rx = Rx[i], ry = Ry[i];
    sx += rx; sy += ry; srr += rx * ry; sxx += rx * rx; syy += ry * ry;
  }
  double ab = 0, aa = 0, bb = 0;
  for (int i = tid; i < 512; i += 256) {
    ab += (double)pab[i]; aa += (double)paa[i]; bb += (double)pbb[i];
  }
  #pragma unroll
  for (int o = 32; o > 0; o >>= 1) {
    sx += __shfl_down(sx, o, 64);  sy += __shfl_down(sy, o, 64);
    srr += __shfl_down(srr, o, 64); sxx += __shfl_down(sxx, o, 64);
    syy += __shfl_down(syy, o, 64); ab += __shfl_down(ab, o, 64);
    aa += __shfl_down(aa, o, 64);  bb += __shfl_down(bb, o, 64);
  }
  __shared__ double t[8][4];
  int lane = tid & 63, w = tid >> 6;
  if (lane == 0) {
    t[0][w] = sx; t[1][w] = sy; t[2][w] = srr; t[3][w] = sxx;
    t[4][w] = syy; t[5][w] = ab; t[6][w] = aa; t[7][w] = bb;
  }
  __syncthreads();
  if (tid == 0) {
    sx  = t[0][0] + t[0][1] + t[0][2] + t[0][3];
    sy  = t[1][0] + t[1][1] + t[1][2] + t[1][3];
    srr = t[2][0] + t[2][1] + t[2][2] + t[2][3];
    sxx = t[3][0] + t[3][1] + t[3][2] + t[3][3];
    syy = t[4][0] + t[4][1] + t[4][2] + t[4][3];
    ab  = t[5][0] + t[5][1] + t[5][2] + t[5][3];
    aa  = t[6][0] + t[6][1] + t[6][2] + t[6][3];
    bb  = t[7][0] + t[7][1] + t[7][2] + t[7][3];
    const double n = (double)NN, n2 = n * n;
    double AB = ab - (2.0 / n) * srr + sx * sy / n2;
    double AA = aa - (2.0 / n) * sxx + sx * sx / n2;
    double BB = bb - (2.0 / n) * syy + sy * sy / n2;
    double xy = AB / n2, xx = AA / n2, yy = BB / n2;
    double r = xy / sqrt(xx * yy + 1e-9);
    out[0] = (float)(1.0 - r);
  }
}

extern "C" void kernel_launch(void* const* d_in, const int* in_sizes, int n_in,
                              void* d_out, int out_size, void* d_ws, size_t ws_size,
                              hipStream_t stream) {
  const float* in0 = (const float*)d_in[0];   // output_1 (N,T,C) fp32
  const float* in1 = (const float*)d_in[1];   // feature  (N,T,C) fp32

  char* ws = (char*)d_ws;
  float* x   = (float*)(ws);                          // 1 MB
  float* y   = (float*)(ws + (1u << 20));             // 1 MB
  float* nx  = (float*)(ws + (2u << 20));             // 4 KB
  float* ny  = (float*)(ws + (2u << 20) + 4096);      // 4 KB
  float* Rx  = (float*)(ws + (2u << 20) + 8192);      // 4 KB  (zeroed)
  float* Ry  = (float*)(ws + (2u << 20) + 12288);     // 4 KB  (zeroed)
  float* pab = (float*)(ws + (2u << 20) + 16384);     // 2 KB  (zeroed)
  float* paa = (float*)(ws + (2u << 20) + 18432);     // 2 KB  (zeroed)
  float* pbb = (float*)(ws + (2u << 20) + 20480);     // 2 KB  (zeroed)

  // zero the atomic accumulators (ws is poisoned 0xAA before every call)
  hipMemsetAsync(ws + (2u << 20) + 8192, 0, 14336, stream);

  mean_norm_kernel<<<2 * NN, 256, 0, stream>>>(in0, in1, x, y, nx, ny);
  dist_kernel<<<dim3(16, 32), 256, 0, stream>>>(x, y, nx, ny, Rx, Ry, pab, paa, pbb);
  finalize_kernel<<<1, 256, 0, stream>>>(Rx, Ry, pab, paa, pbb, (float*)d_out);
}

// Round 3
// 183.411 us; speedup vs baseline: 1.1776x; 1.1776x over previous
//
#include <hip/hip_runtime.h>
#include <math.h>

#define NN 1024
#define CC 256
#define TT 64

// ---------------- kernel 1: fused time-mean + row norm ----------------
// 2048 blocks: block b handles tensor (b>>10), row (b&1023). 256 threads.
// Reads a contiguous 64KB (T=64 x C=256 fp32) per block, fully coalesced.
__global__ __launch_bounds__(256) void mean_norm_kernel(
    const float* __restrict__ in0, const float* __restrict__ in1,
    float* __restrict__ x, float* __restrict__ y,
    float* __restrict__ nx, float* __restrict__ ny) {
  int b = blockIdx.x;
  int m = b >> 10;
  int n = b & (NN - 1);
  const float* in = (m ? in1 : in0) + (size_t)n * (TT * CC);
  float* xo = m ? y : x;
  float* no = m ? ny : nx;
  int tid = threadIdx.x;
  int c4 = tid & 63;            // float4 channel index (64 per row)
  int tq = tid >> 6;            // wave id = time-quarter
  const float4* src = (const float4*)in + c4;
  float4 s0 = make_float4(0.f, 0.f, 0.f, 0.f);
  float4 s1 = make_float4(0.f, 0.f, 0.f, 0.f);
  #pragma unroll
  for (int t = 0; t < 8; ++t) {
    float4 v = src[(tq * 16 + 2 * t) * (CC / 4)];
    float4 w = src[(tq * 16 + 2 * t + 1) * (CC / 4)];
    s0.x += v.x; s0.y += v.y; s0.z += v.z; s0.w += v.w;
    s1.x += w.x; s1.y += w.y; s1.z += w.z; s1.w += w.w;
  }
  float4 s = make_float4(s0.x + s1.x, s0.y + s1.y, s0.z + s1.z, s0.w + s1.w);
  __shared__ float4 red[3][64];
  if (tq) red[tq - 1][c4] = s;
  __syncthreads();
  if (tq == 0) {
    #pragma unroll
    for (int w = 0; w < 3; ++w) {
      float4 v = red[w][c4];
      s.x += v.x; s.y += v.y; s.z += v.z; s.w += v.w;
    }
    const float inv = 1.0f / TT;
    s.x *= inv; s.y *= inv; s.z *= inv; s.w *= inv;
    ((float4*)(xo + (size_t)n * CC))[c4] = s;
    float ssq = fmaf(s.x, s.x, fmaf(s.y, s.y, fmaf(s.z, s.z, s.w * s.w)));
    #pragma unroll
    for (int o = 32; o > 0; o >>= 1) ssq += __shfl_down(ssq, o, 64);
    if (tid == 0) no[n] = ssq;
  }
}

// ---------------- kernel 2: fused pairwise-distance + reductions ----------------
// Grid (16,16): 64x64 tile, 256 threads, 4x4 microtile, both matrices.
// XOR-swizzled LDS tiles: element (row, g[float4]) stored at phys group
// g ^ ((row>>2)&7). All LDS ops are b128, <=2-way bank aliasing (free).
// Outputs (no atomics): per-(coltile,row) row-sum partials Rxp/Ryp,
// per-block product partials pab/paa/pbb.
__global__ __launch_bounds__(256) void dist_kernel(
    const float* __restrict__ x, const float* __restrict__ y,
    const float* __restrict__ nx, const float* __restrict__ ny,
    float* __restrict__ Rxp, float* __restrict__ Ryp,
    float* __restrict__ pab, float* __restrict__ paa, float* __restrict__ pbb) {
  __shared__ float4 tAX[64][16];
  __shared__ float4 tAY[64][16];
  __shared__ float4 tBX[64][16];
  __shared__ float4 tBY[64][16];

  int tid = threadIdx.x;
  int tx = tid & 15, ty = tid >> 4;
  int ti = blockIdx.y * 64, tj = blockIdx.x * 64;

  float accx[4][4] = {};
  float accy[4][4] = {};

  const float4* gx = (const float4*)x;   // [row][64] float4 groups
  const float4* gy = (const float4*)y;

  for (int kc = 0; kc < 64; kc += 16) {  // 4 chunks of 16 float4-groups (64 ch)
    if (kc) __syncthreads();
    #pragma unroll
    for (int s = 0; s < 4; ++s) {
      int f4 = tid + s * 256;            // 0..1023
      int r = f4 >> 4;                   // 0..63
      int g = f4 & 15;
      int pg = g ^ ((r >> 2) & 7);
      tAX[r][pg] = gx[(size_t)(ti + r) * 64 + kc + g];
      tAY[r][pg] = gy[(size_t)(ti + r) * 64 + kc + g];
      tBX[r][pg] = gx[(size_t)(tj + r) * 64 + kc + g];
      tBY[r][pg] = gy[(size_t)(tj + r) * 64 + kc + g];
    }
    __syncthreads();
    #pragma unroll
    for (int g = 0; g < 16; ++g) {
      float4 bxv[4], byv[4];
      int pgb = g ^ (tx & 7);
      #pragma unroll
      for (int q = 0; q < 4; ++q) {
        bxv[q] = tBX[4 * tx + q][pgb];
        byv[q] = tBY[4 * tx + q][pgb];
      }
      int pga = g ^ (ty & 7);
      #pragma unroll
      for (int p = 0; p < 4; ++p) {
        float4 ax = tAX[4 * ty + p][pga];
        float4 ay = tAY[4 * ty + p][pga];
        #pragma unroll
        for (int q = 0; q < 4; ++q) {
          accx[p][q] = fmaf(ax.w, bxv[q].w, fmaf(ax.z, bxv[q].z,
                       fmaf(ax.y, bxv[q].y, fmaf(ax.x, bxv[q].x, accx[p][q]))));
          accy[p][q] = fmaf(ay.w, byv[q].w, fmaf(ay.z, byv[q].z,
                       fmaf(ay.y, byv[q].y, fmaf(ay.x, byv[q].x, accy[p][q]))));
        }
      }
    }
  }

  // epilogue: d = sqrt(max(ni+nj-2g,0)+1e-12); accumulate sums
  float nix[4], niy[4], njx[4], njy[4];
  #pragma unroll
  for (int p = 0; p < 4; ++p) { nix[p] = nx[ti + 4 * ty + p]; niy[p] = ny[ti + 4 * ty + p]; }
  #pragma unroll
  for (int q = 0; q < 4; ++q) { njx[q] = nx[tj + 4 * tx + q]; njy[q] = ny[tj + 4 * tx + q]; }

  float ab = 0.f, aa = 0.f, bb = 0.f;
  #pragma unroll
  for (int p = 0; p < 4; ++p) {
    float rsx = 0.f, rsy = 0.f;
    #pragma unroll
    for (int q = 0; q < 4; ++q) {
      float dxv = sqrtf(fmaxf(nix[p] + njx[q] - 2.f * accx[p][q], 0.f) + 1e-12f);
      float dyv = sqrtf(fmaxf(niy[p] + njy[q] - 2.f * accy[p][q], 0.f) + 1e-12f);
      ab = fmaf(dxv, dyv, ab);
      aa = fmaf(dxv, dxv, aa);
      bb = fmaf(dyv, dyv, bb);
      rsx += dxv; rsy += dyv;
    }
    // reduce row partial over the 16 tx-lanes of this ty-group
    #pragma unroll
    for (int o = 8; o > 0; o >>= 1) {
      rsx += __shfl_down(rsx, o, 16);
      rsy += __shfl_down(rsy, o, 16);
    }
    if (tx == 0) {
      Rxp[blockIdx.x * NN + ti + 4 * ty + p] = rsx;
      Ryp[blockIdx.x * NN + ti + 4 * ty + p] = rsy;
    }
  }

  // block-level product partials
  #pragma unroll
  for (int o = 32; o > 0; o >>= 1) {
    ab += __shfl_down(ab, o, 64);
    aa += __shfl_down(aa, o, 64);
    bb += __shfl_down(bb, o, 64);
  }
  __shared__ float redp[3][4];
  int wv = tid >> 6;
  if ((tid & 63) == 0) { redp[0][wv] = ab; redp[1][wv] = aa; redp[2][wv] = bb; }
  __syncthreads();
  if (tid == 0) {
    int blk = blockIdx.y * 16 + blockIdx.x;
    pab[blk] = redp[0][0] + redp[0][1] + redp[0][2] + redp[0][3];
    paa[blk] = redp[1][0] + redp[1][1] + redp[1][2] + redp[1][3];
    pbb[blk] = redp[2][0] + redp[2][1] + redp[2][2] + redp[2][3];
  }
}

// ---------------- kernel 3: finalize ----------------
// <A,B> = S(DxDy) - (2/n) S(Rx.Ry) + Sx.Sy/n^2  (H idempotent, D symmetric)
__global__ __launch_bounds__(256) void finalize_kernel(
    const float* __restrict__ Rxp, const float* __restrict__ Ryp,
    const float* __restrict__ pab, const float* __restrict__ paa,
    const float* __restrict__ pbb, float* __restrict__ out) {
  int tid = threadIdx.x;
  const float4* rx4 = (const float4*)Rxp;
  const float4* ry4 = (const float4*)Ryp;
  float4 Rx = make_float4(0.f, 0.f, 0.f, 0.f);
  float4 Ry = make_float4(0.f, 0.f, 0.f, 0.f);
  #pragma unroll
  for (int b = 0; b < 16; ++b) {
    float4 v = rx4[b * 256 + tid];
    Rx.x += v.x; Rx.y += v.y; Rx.z += v.z; Rx.w += v.w;
    float4 w = ry4[b * 256 + tid];
    Ry.x += w.x; Ry.y += w.y; Ry.z += w.z; Ry.w += w.w;
  }
  double sx = (double)Rx.x + Rx.y + Rx.z + Rx.w;
  double sy = (double)Ry.x + Ry.y + Ry.z + Ry.w;
  double srr = (double)Rx.x * Ry.x + (double)Rx.y * Ry.y + (double)Rx.z * Ry.z + (double)Rx.w * Ry.w;
  double sxx = (double)Rx.x * Rx.x + (double)Rx.y * Rx.y + (double)Rx.z * Rx.z + (double)Rx.w * Rx.w;
  double syy = (double)Ry.x * Ry.x + (double)Ry.y * Ry.y + (double)Ry.z * Ry.z + (double)Ry.w * Ry.w;
  double ab = (double)pab[tid];   // 256 partials, 256 threads
  double aa = (double)paa[tid];
  double bb = (double)pbb[tid];
  #pragma unroll
  for (int o = 32; o > 0; o >>= 1) {
    sx += __shfl_down(sx, o, 64);  sy += __shfl_down(sy, o, 64);
    srr += __shfl_down(srr, o, 64); sxx += __shfl_down(sxx, o, 64);
    syy += __shfl_down(syy, o, 64); ab += __shfl_down(ab, o, 64);
    aa += __shfl_down(aa, o, 64);  bb += __shfl_down(bb, o, 64);
  }
  __shared__ double t[8][4];
  int lane = tid & 63, w = tid >> 6;
  if (lane == 0) {
    t[0][w] = sx; t[1][w] = sy; t[2][w] = srr; t[3][w] = sxx;
    t[4][w] = syy; t[5][w] = ab; t[6][w] = aa; t[7][w] = bb;
  }
  __syncthreads();
  if (tid == 0) {
    sx  = t[0][0] + t[0][1] + t[0][2] + t[0][3];
    sy  = t[1][0] + t[1][1] + t[1][2] + t[1][3];
    srr = t[2][0] + t[2][1] + t[2][2] + t[2][3];
    sxx = t[3][0] + t[3][1] + t[3][2] + t[3][3];
    syy = t[4][0] + t[4][1] + t[4][2] + t[4][3];
    ab  = t[5][0] + t[5][1] + t[5][2] + t[5][3];
    aa  = t[6][0] + t[6][1] + t[6][2] + t[6][3];
    bb  = t[7][0] + t[7][1] + t[7][2] + t[7][3];
    const double n = (double)NN, n2 = n * n;
    double AB = ab - (2.0 / n) * srr + sx * sy / n2;
    double AA = aa - (2.0 / n) * sxx + sx * sx / n2;
    double BB = bb - (2.0 / n) * syy + sy * sy / n2;
    double xy = AB / n2, xx = AA / n2, yy = BB / n2;
    double r = xy / sqrt(xx * yy + 1e-9);
    out[0] = (float)(1.0 - r);
  }
}

extern "C" void kernel_launch(void* const* d_in, const int* in_sizes, int n_in,
                              void* d_out, int out_size, void* d_ws, size_t ws_size,
                              hipStream_t stream) {
  const float* in0 = (const float*)d_in[0];   // output_1 (N,T,C) fp32
  const float* in1 = (const float*)d_in[1];   // feature  (N,T,C) fp32

  char* ws = (char*)d_ws;
  float* x   = (float*)(ws);                          // 1 MB
  float* y   = (float*)(ws + (1u << 20));             // 1 MB
  float* nx  = (float*)(ws + (2u << 20));             // 4 KB
  float* ny  = (float*)(ws + (2u << 20) + 4096);      // 4 KB
  float* Rxp = (float*)(ws + (2u << 20) + 8192);      // 64 KB (16x1024)
  float* Ryp = (float*)(ws + (2u << 20) + 8192 + 65536);        // 64 KB
  float* pab = (float*)(ws + (2u << 20) + 8192 + 2 * 65536);    // 1 KB
  float* paa = (float*)(ws + (2u << 20) + 8192 + 2 * 65536 + 1024);
  float* pbb = (float*)(ws + (2u << 20) + 8192 + 2 * 65536 + 2048);

  mean_norm_kernel<<<2 * NN, 256, 0, stream>>>(in0, in1, x, y, nx, ny);
  dist_kernel<<<dim3(16, 16), 256, 0, stream>>>(x, y, nx, ny, Rxp, Ryp, pab, paa, pbb);
  finalize_kernel<<<1, 256, 0, stream>>>(Rxp, Ryp, pab, paa, pbb, (float*)d_out);
}